// Round 3
// baseline (19.294 us; speedup 1.0000x reference)
//
#include <hip/hip_runtime.h>
#include <hip/hip_bf16.h>

// CoFiSet scoring: out[0][b] = mean_s(u_b . v_{p_bs} + bi_{p_bs}),
//                  out[1][b] = u_b . v_{n_b} + bi_{n_b}
// One wave64 per batch row. lane = 16*r + q:
//   r = S-slice (0..3), handles pos items 5r..5r+4 (slice 0 also does neg)
//   q = 16B chunk of the 256B embedding row (float4)
// Max occupancy test: 16384 waves, every vmem instr = 4 rows x 256B = 16 lines.

#define DIM 64
#define NPOS 20

__global__ __launch_bounds__(256) void cofiset_kernel(
    const float* __restrict__ U,
    const float* __restrict__ V,
    const float* __restrict__ bi,
    const int*   __restrict__ user_id,
    const int*   __restrict__ pos_item_id,
    const int*   __restrict__ neg_item_id,
    float* __restrict__ out,
    int B)
{
    const int row  = (int)((blockIdx.x * blockDim.x + threadIdx.x) >> 6);
    const int lane = (int)(threadIdx.x & 63);
    const int r    = lane >> 4;         // S-slice
    const int q    = lane & 15;         // float4 chunk within row
    if (row >= B) return;

    // ---- indices ----
    const int uid  = user_id[row];
    const int nidx = neg_item_id[row];
    // lane (16r+q), q<5 owns pos item 5r+q
    int pidx = 0;
    float pb = 0.0f;
    if (q < 5) {
        pidx = pos_item_id[row * NPOS + r * 5 + q];
        pb   = bi[pidx];
    }

    // ---- user embedding chunk (lanes across slices share lines; HW merges) ----
    const float4 u4 = *(const float4*)&U[(size_t)uid * DIM + q * 4];

    // ---- positive accumulation: slice r does items 5r..5r+4 ----
    const int grp = r << 4;             // base lane of this slice
    float acc = pb;                     // bias partials fold into the reduction
    #pragma unroll
    for (int j = 0; j < 5; ++j) {
        const int idx = __shfl(pidx, grp + j);
        const float4 v4 = *(const float4*)&V[(size_t)idx * DIM + q * 4];
        acc = fmaf(u4.x, v4.x, acc);
        acc = fmaf(u4.y, v4.y, acc);
        acc = fmaf(u4.z, v4.z, acc);
        acc = fmaf(u4.w, v4.w, acc);
    }

    // ---- negative item: slice 0 only ----
    float accn = 0.0f;
    if (r == 0) {
        const float4 vn = *(const float4*)&V[(size_t)nidx * DIM + q * 4];
        accn = u4.x * vn.x + u4.y * vn.y + u4.z * vn.z + u4.w * vn.w;
    }

    // ---- full-wave butterfly sums all 20 dots + 20 biases ----
    #pragma unroll
    for (int off = 32; off >= 1; off >>= 1) {
        acc += __shfl_xor(acc, off);
    }
    // ---- neg reduce within slice 0 (16 lanes) ----
    #pragma unroll
    for (int off = 8; off >= 1; off >>= 1) {
        accn += __shfl_xor(accn, off);
    }

    if (lane == 0) {
        out[row]     = acc * (1.0f / (float)NPOS);
        out[B + row] = accn + bi[nidx];
    }
}

extern "C" void kernel_launch(void* const* d_in, const int* in_sizes, int n_in,
                              void* d_out, int out_size, void* d_ws, size_t ws_size,
                              hipStream_t stream) {
    const float* U   = (const float*)d_in[0];
    const float* V   = (const float*)d_in[1];
    const float* bi  = (const float*)d_in[2];
    const int* user_id     = (const int*)d_in[3];
    const int* pos_item_id = (const int*)d_in[4];
    const int* neg_item_id = (const int*)d_in[5];
    float* out = (float*)d_out;

    const int B = in_sizes[3];              // 16384
    const int rows_per_block = 4;           // 4 waves/block, 1 row/wave
    const int grid = (B + rows_per_block - 1) / rows_per_block;   // 4096

    cofiset_kernel<<<grid, 256, 0, stream>>>(U, V, bi, user_id, pos_item_id,
                                             neg_item_id, out, B);
}